// Round 9
// baseline (248.960 us; speedup 1.0000x reference)
//
#include <hip/hip_runtime.h>
#include <stdint.h>

#define H 4096
#define W 4096
#define EOFS 5
#define K_TOP 4096
#define NB 65536
#define SLOT_CAP 8192
#define RPB 8                  // rows per collect block
#define NRG 511                // rowgroups (4086 rows / 8)
#define NCG 4                  // colgroups (1024 cols each)
#define NBLK (NRG * NCG)       // 2044 collect blocks
#define CBUF 512               // per-block candidate LDS buffer (4 KB; mean ~220)
#define EMIT_LDS (K_TOP + 128)

// ws layout (bytes):
//   0       : hist u32[65536]      (256 KB)
//   262144  : base u32[65536]      (256 KB)  top chunks only; mutated by scatter
//   526336  : pivot u32 ; 526340: candCount u32
//   526848  : slots u64[8192]      (64 KB)
//   655360  : cand u64[cand_cap]   (only if ws_size permits)

// Monotone value->bucket map, flattened for the ~x^9 CDF of NMS survivors.
// Pure multiplies -> no FMA contraction -> bit-stable across kernels.
__device__ __forceinline__ unsigned int bucket_of(float s) {
    float u = s * s;
    float u2 = u * u;
    float u4 = u2 * u2;
    float s9 = u4 * s;
    unsigned int b = (unsigned int)(s9 * 65536.0f);
    return b > 65535u ? 65535u : b;
}

__global__ void zero_kernel(unsigned int* hist, unsigned int* pivot,
                            unsigned int* candCount) {
    int p = blockIdx.x * blockDim.x + threadIdx.x;
    if (p < NB) hist[p] = 0u;
    if (p == 0) { pivot[0] = 0u; candCount[0] = 0u; }
}

// Load 6 consecutive floats [j0-1, j0+4]; j0 is 16B-aligned.
#define LOADROW6(arr, p)                                                       \
    {                                                                          \
        const float* _p = (p);                                                 \
        arr[0] = _p[-1];                                                       \
        float4 _q = *(const float4*)_p;                                        \
        arr[1] = _q.x; arr[2] = _q.y; arr[3] = _q.z; arr[4] = _q.w;            \
        arr[5] = _p[4];                                                        \
    }

// Single full-image pass. 2044 blocks x 256 thr x 4 cols x 8 rows; 3-row
// window rotates in registers; separable-max NMS (exact). Survivors -> LDS
// buf ONLY (no global atomics inside the load loop — they poison vmcnt and
// serialize the row pipeline). Post-loop: batch hist atomics + cand append.
__global__ __launch_bounds__(256)
void collect_kernel(const float* __restrict__ x, const int* __restrict__ vmask,
                    unsigned int* __restrict__ hist,
                    unsigned long long* __restrict__ cand,
                    unsigned int* __restrict__ candCount,
                    unsigned int cand_cap, int do_cand) {
    __shared__ unsigned long long buf[CBUF];
    __shared__ unsigned int cnt, gbase;
    int t = threadIdx.x;
    if (t == 0) cnt = 0u;
    __syncthreads();

    int rowgroup = (int)blockIdx.x >> 2;
    int cg = (int)blockIdx.x & 3;
    int j0 = cg * 1024 + t * 4;
    bool active = !((cg == 0 && t == 0) || (cg == NCG - 1 && t == 255));
    int r0 = EOFS + rowgroup * RPB;
    int rend = r0 + RPB - 1;
    if (rend > H - 1 - EOFS) rend = H - 1 - EOFS;

    float A[6], B[6], C[6], vm[6];
    if (active) {
        LOADROW6(A, x + (size_t)(r0 - 1) * W + j0);
        LOADROW6(B, x + (size_t)r0 * W + j0);
    }
    for (int i = r0; i <= rend; ++i) {
        if (active) {
            LOADROW6(C, x + (size_t)(i + 1) * W + j0);
            #pragma unroll
            for (int c = 0; c < 6; ++c)
                vm[c] = fmaxf(fmaxf(A[c], B[c]), C[c]);   // -> v_max3_f32
            #pragma unroll
            for (int k = 1; k <= 4; ++k) {
                int j = j0 + k - 1;
                if (j >= EOFS && j <= W - 1 - EOFS) {
                    float e = B[k];
                    if (e > 0.0f) {
                        float m = fmaxf(fmaxf(vm[k - 1], vm[k]), vm[k + 1]);
                        if (e >= m) {
                            float dii = (A[k] - 2.0f * e) + C[k];
                            float djj = (B[k - 1] - 2.0f * e) + B[k + 1];
                            float dij = 0.25f * (((A[k - 1] - A[k + 1]) - C[k - 1]) + C[k + 1]);
                            float det = dii * djj - dij * dij;
                            if (det > 0.0f) {
                                float tr = dii + djj;
                                if (tr * tr / det <= 12.1f) {
                                    if (vmask[(size_t)i * W + j] != 0) {
                                        unsigned int pos = atomicAdd(&cnt, 1u);
                                        if (pos < CBUF) {
                                            unsigned int fb = __float_as_uint(e);
                                            unsigned int idx =
                                                (unsigned int)i * W + (unsigned int)j;
                                            buf[pos] =
                                                ((unsigned long long)fb << 32) |
                                                (unsigned int)(~idx);
                                        }
                                    }
                                }
                            }
                        }
                    }
                }
            }
            #pragma unroll
            for (int c = 0; c < 6; ++c) { A[c] = B[c]; B[c] = C[c]; }
        }
    }

    __syncthreads();
    unsigned int c = cnt;
    if (c > CBUF) c = CBUF;
    // Batch hist atomics from the LDS buf (fire-and-forget; one drain at end).
    for (unsigned int p = t; p < c; p += 256) {
        unsigned long long k = buf[p];
        float s = __uint_as_float((unsigned int)(k >> 32));
        atomicAdd(&hist[bucket_of(s)], 1u);
    }
    if (do_cand) {
        if (t == 0) gbase = atomicAdd(candCount, c);   // ONE global atomic/block
        __syncthreads();
        unsigned int g0 = gbase;
        for (unsigned int p = t; p < c; p += 256)
            if (g0 + p < cand_cap) cand[g0 + p] = buf[p];
    }
}

// Single block: scan hist from the TOP in 1024-bucket chunks; write base[]
// (= #candidates strictly above bucket) and find pivot; stop once the
// cumulative count reaches K_TOP (only ~1-2 chunks ever visited).
__global__ __launch_bounds__(1024)
void pivotbase_kernel(const unsigned int* __restrict__ hist,
                      unsigned int* __restrict__ base,
                      unsigned int* __restrict__ pivotOut) {
    __shared__ unsigned int s[1024];
    __shared__ unsigned int carry_s;
    int t = threadIdx.x;
    if (t == 0) carry_s = 0u;
    __syncthreads();
    for (int chunk = NB - 1024; chunk >= 0; chunk -= 1024) {
        unsigned int carry = carry_s;
        unsigned int h = hist[chunk + t];
        s[t] = h;
        __syncthreads();
        // inclusive suffix scan: s[t] = sum_{u >= t} h[u]
        for (int off = 1; off < 1024; off <<= 1) {
            unsigned int v = (t + off < 1024) ? s[t + off] : 0u;
            __syncthreads();
            s[t] += v;
            __syncthreads();
        }
        unsigned int bb = carry + s[t] - h;       // strictly above bucket chunk+t
        base[chunk + t] = bb;
        if (bb < (unsigned int)K_TOP && bb + h >= (unsigned int)K_TOP)
            pivotOut[0] = (unsigned int)(chunk + t);
        unsigned int total = s[0];
        __syncthreads();
        if (t == 0) carry_s = carry + total;
        __syncthreads();
        if (carry + total >= (unsigned int)K_TOP) break;   // block-uniform
    }
}

// Scatter from the candidate list into rank-contiguous slots.
__global__ __launch_bounds__(256)
void scatter_cand_kernel(const unsigned long long* __restrict__ cand,
                         const unsigned int* __restrict__ candCount,
                         const unsigned int* __restrict__ pivotPtr,
                         unsigned int* __restrict__ base,
                         unsigned long long* __restrict__ slots,
                         unsigned int cand_cap) {
    unsigned int n = *candCount;
    if (n > cand_cap) n = cand_cap;
    unsigned int pivot = *pivotPtr;
    unsigned int stride = gridDim.x * blockDim.x;
    for (unsigned int p = blockIdx.x * blockDim.x + threadIdx.x; p < n; p += stride) {
        unsigned long long k = cand[p];
        unsigned int fb = (unsigned int)(k >> 32);
        unsigned int bkt = bucket_of(__uint_as_float(fb));
        if (bkt >= pivot) {
            unsigned int pos = atomicAdd(&base[bkt], 1u);
            if (pos < (unsigned int)SLOT_CAP) slots[pos] = k;
        }
    }
}

// Fallback (small ws): recompute stencil for the scatter pass.
__global__ void scatter_full_kernel(const float* __restrict__ x,
                                    const int* __restrict__ vmask,
                                    const unsigned int* __restrict__ pivotPtr,
                                    unsigned int* __restrict__ base,
                                    unsigned long long* __restrict__ slots) {
    int j = EOFS + blockIdx.x * blockDim.x + threadIdx.x;
    int i = EOFS + blockIdx.y;
    if (j > W - 1 - EOFS) return;
    const float* r0p = x + (size_t)(i - 1) * W + j;
    const float* r1p = x + (size_t)i * W + j;
    const float* r2p = x + (size_t)(i + 1) * W + j;
    float a = r0p[-1], b = r0p[0], c = r0p[1];
    float d = r1p[-1], e = r1p[0], f = r1p[1];
    float g = r2p[-1], h2 = r2p[0], i2 = r2p[1];
    if (!(e > 0.0f)) return;
    float m = fmaxf(fmaxf(fmaxf(a, b), fmaxf(c, d)),
                    fmaxf(fmaxf(f, g), fmaxf(h2, i2)));
    if (!(e >= m)) return;
    float dii = (b - 2.0f * e) + h2;
    float djj = (d - 2.0f * e) + f;
    float dij = 0.25f * (((a - c) - g) + i2);
    float det = dii * djj - dij * dij;
    if (!(det > 0.0f)) return;
    float tr = dii + djj;
    if (!(tr * tr / det <= 12.1f)) return;
    if (vmask[(size_t)i * W + j] == 0) return;
    unsigned int bkt = bucket_of(e);
    if (bkt >= pivotPtr[0]) {
        unsigned int pos = atomicAdd(&base[bkt], 1u);
        if (pos < (unsigned int)SLOT_CAP) {
            unsigned int idx = (unsigned int)i * W + (unsigned int)j;
            slots[pos] = ((unsigned long long)__float_as_uint(e) << 32)
                       | (unsigned int)(~idx);
        }
    }
}

// Single block: stage slots[0 .. K_TOP+128) in LDS, per-bucket insertion sort
// in place (slices are disjoint), write final ranks.
__global__ __launch_bounds__(1024, 1)
void emit_kernel(const unsigned int* __restrict__ baseAfter,
                 const unsigned int* __restrict__ pivotPtr,
                 const unsigned long long* __restrict__ slots,
                 float* __restrict__ out) {
    __shared__ unsigned long long lds[EMIT_LDS];
    int t = threadIdx.x;
    for (int p = t; p < EMIT_LDS; p += 1024) lds[p] = slots[p];
    __syncthreads();
    unsigned int pivot = pivotPtr[0];
    for (int b = (int)pivot + t; b < NB; b += 1024) {
        unsigned int start = (b == 65535) ? 0u : baseAfter[b + 1];
        unsigned int end = baseAfter[b];
        if (end > (unsigned int)SLOT_CAP) end = (unsigned int)SLOT_CAP;
        if (end <= start || start >= (unsigned int)K_TOP) continue;
        unsigned int len = end - start;
        if (len > 128u) len = 128u;
        if (start + len > (unsigned int)EMIT_LDS) len = (unsigned int)EMIT_LDS - start;
        unsigned long long* a = &lds[start];
        for (unsigned int r = 1; r < len; ++r) {           // desc insertion sort
            unsigned long long key = a[r];
            int q = (int)r - 1;
            while (q >= 0 && a[q] < key) { a[q + 1] = a[q]; --q; }
            a[q + 1] = key;
        }
        unsigned int emitN = len;
        if (start + emitN > (unsigned int)K_TOP) emitN = (unsigned int)K_TOP - start;
        for (unsigned int r = 0; r < emitN; ++r) {
            unsigned long long key = a[r];
            unsigned int fb = (unsigned int)(key >> 32);
            unsigned int idx = ~((unsigned int)key);
            unsigned int rank = start + r;
            out[rank]             = (float)(idx >> 12);       // row
            out[K_TOP + rank]     = (float)(idx & (W - 1));   // col
            out[2 * K_TOP + rank] = __uint_as_float(fb);      // score
        }
    }
}

extern "C" void kernel_launch(void* const* d_in, const int* in_sizes, int n_in,
                              void* d_out, int out_size, void* d_ws, size_t ws_size,
                              hipStream_t stream) {
    const float* score = (const float*)d_in[0];
    const int* vmask = (const int*)d_in[1];
    unsigned char* ws = (unsigned char*)d_ws;
    unsigned int* hist      = (unsigned int*)ws;
    unsigned int* base      = (unsigned int*)(ws + 262144);
    unsigned int* pivot     = (unsigned int*)(ws + 526336);
    unsigned int* candCount = (unsigned int*)(ws + 526340);
    unsigned long long* slots = (unsigned long long*)(ws + 526848);
    unsigned long long* cand  = (unsigned long long*)(ws + 655360);
    float* out = (float*)d_out;

    unsigned int cand_cap = 0;
    int do_cand = 0;
    if (ws_size >= 655360ull + 8ull * 1000000ull) {       // proven gate
        size_t cap = (ws_size - 655360ull) / 8ull;
        if (cap > 2097152ull) cap = 2097152ull;
        cand_cap = (unsigned int)cap;
        do_cand = 1;
    }

    zero_kernel<<<(NB + 255) / 256, 256, 0, stream>>>(hist, pivot, candCount);

    collect_kernel<<<NBLK, 256, 0, stream>>>(score, vmask, hist, cand,
                                             candCount, cand_cap, do_cand);
    pivotbase_kernel<<<1, 1024, 0, stream>>>(hist, base, pivot);

    if (do_cand) {
        scatter_cand_kernel<<<512, 256, 0, stream>>>(cand, candCount, pivot,
                                                     base, slots, cand_cap);
    } else {
        dim3 blk(256, 1, 1), grd(16, H - 2 * EOFS, 1);
        scatter_full_kernel<<<grd, blk, 0, stream>>>(score, vmask, pivot, base, slots);
    }
    emit_kernel<<<1, 1024, 0, stream>>>(base, pivot, slots, out);
}